// Round 15
// baseline (78.679 us; speedup 1.0000x reference)
//
#include <hip/hip_runtime.h>

typedef unsigned short u16;
typedef unsigned int u32;
typedef __bf16 bf16x8 __attribute__((ext_vector_type(8)));
typedef float f32x4 __attribute__((ext_vector_type(4)));
typedef u32 u32x4 __attribute__((ext_vector_type(4)));

#define AS1 __attribute__((address_space(1)))
#define AS3 __attribute__((address_space(3)))

// kTr[((t*2+nh)*2+nt)*2+kb][lane][j] : per-lane-ordered repack -> every
// B-load is one fully-contiguous 1KB wave read (8 fully-used cachelines).
__device__ __align__(16) u16 g_kTr[27 * 8 * 512];

__device__ __forceinline__ u32 pack_bf(float a, float b) {
    u32 ua = __float_as_uint(a) + 0x8000u;
    u32 ub = __float_as_uint(b) + 0x8000u;
    return __builtin_amdgcn_perm(ub, ua, 0x07060302u);
}

// ---------------------------------------------------------------------------
// prep: blocks 0..26 build kTr (+ fold self-connection into center tap);
//       blocks 27.. convert x fp32 -> bf16 (+ zero page in block 27).
// ---------------------------------------------------------------------------
__global__ __launch_bounds__(256) void prep(
    const float* __restrict__ Wsc0, const float* __restrict__ Wsc1,
    const float* __restrict__ w1, const float* __restrict__ w2,
    const float* __restrict__ w3, const float* __restrict__ w4,
    const float* __restrict__ x, u16* __restrict__ xb, u32* __restrict__ zp)
{
    const int tid = threadIdx.x;
    if (blockIdx.x < 27) {
        if (tid >= 64) return;
        const int t = blockIdx.x;
        const int c = tid;
        const int dx = t / 9 - 1, dy = (t / 3) % 3 - 1, dz = t % 3 - 1;
        const float d = sqrtf((float)(dx * dx + dy * dy + dz * dz));
        const float step = 1.5f / 9.0f;
        float emb[8];
#pragma unroll
        for (int k = 0; k < 8; ++k) {
            float diff = (d - (float)(k + 1) * step) / step;
            float q = diff * diff;
            emb[k] = (q < 1.0f) ? 1.14136f * expf(2.0f - 2.0f / (1.0f - q)) : 0.0f;
        }
        const float dn = fmaxf(d, 1e-12f);
        const float s3 = 1.7320508075688772f;
        const float sh1[3] = { s3 * dx / dn, s3 * dy / dn, s3 * dz / dn };
        const float alpha  = 0.17677669529663687f;
        const float alpha3 = alpha * 0.57735026918962576f;

        const int base2 = ((t * 2 + (c >> 5)) * 2 + ((c >> 4) & 1)) * 2;
        const int l15c  = c & 15;
        auto put = [&](int r, float v) {
            u32 u = __float_as_uint(v);
            u += 0x7FFFu + ((u >> 16) & 1u);
            g_kTr[(base2 + (r >> 5)) * 512 + (((r >> 3) & 3) * 16 + l15c) * 8 + (r & 7)] =
                (u16)(u >> 16);
        };

        if (c < 16) {
            const int o = c;
#pragma unroll
            for (int i = 0; i < 16; ++i) {
                float W1 = 0.f, W4 = 0.f;
#pragma unroll
                for (int k = 0; k < 8; ++k) {
                    W1 += emb[k] * w1[k * 256 + i * 16 + o];
                    W4 += emb[k] * w4[k * 256 + i * 16 + o];
                }
                W1 *= (1.0f / 27.0f); W4 *= (1.0f / 27.0f);
                float v0 = alpha * W1;
                if (t == 13) v0 += 0.25f * Wsc0[i * 16 + o];
                put(i, v0);
                const float base = alpha3 * W4;
#pragma unroll
                for (int m = 0; m < 3; ++m) put(16 + 3 * i + m, base * sh1[m]);
            }
        } else {
            const int o = (c - 16) / 3, nc = (c - 16) % 3;
#pragma unroll
            for (int i = 0; i < 16; ++i) {
                float W2 = 0.f, W3 = 0.f;
#pragma unroll
                for (int k = 0; k < 8; ++k) {
                    W2 += emb[k] * w2[k * 256 + i * 16 + o];
                    W3 += emb[k] * w3[k * 256 + i * 16 + o];
                }
                W2 *= (1.0f / 27.0f); W3 *= (1.0f / 27.0f);
                put(i, alpha * W2 * sh1[nc]);
#pragma unroll
                for (int m = 0; m < 3; ++m) {
                    float v = (m == nc) ? alpha * W3 : 0.0f;
                    if (t == 13 && m == nc) v += 0.25f * Wsc1[i * 16 + o];
                    put(16 + 3 * i + m, v);
                }
            }
        }
    } else {
        const int bid2 = blockIdx.x - 27;
        if (bid2 == 0) {
            u32x4 z = {0u, 0u, 0u, 0u};
            *reinterpret_cast<u32x4*>(zp + tid * 4) = z;   // 4KB zero page
        }
        const size_t base = ((size_t)bid2 * 256 + tid) * 8;
        const float4* s = reinterpret_cast<const float4*>(x + base);
        float4 v0 = s[0], v1 = s[1];
        u32x4 p;
        p[0] = pack_bf(v0.x, v0.y); p[1] = pack_bf(v0.z, v0.w);
        p[2] = pack_bf(v1.x, v1.y); p[3] = pack_bf(v1.z, v1.w);
        *reinterpret_cast<u32x4*>(xb + base) = p;
    }
}

// ---------------------------------------------------------------------------
// Shared macros
// ---------------------------------------------------------------------------
#define ISSUE_B(s, t) \
  { const char* _p = bTr + (t) * 8192; \
    asm volatile("global_load_dwordx4 %0, %4, off\n\t" \
                 "global_load_dwordx4 %1, %4, off offset:1024\n\t" \
                 "global_load_dwordx4 %2, %4, off offset:2048\n\t" \
                 "global_load_dwordx4 %3, %4, off offset:3072" \
                 : "=&v"(B##s##0), "=&v"(B##s##1), "=&v"(B##s##2), "=&v"(B##s##3) \
                 : "v"(_p)); }

#define LOADA2(s, i0, i1, RCC) { \
  const int _r  = rbase + (RCC); \
  const int _o0 = _r * 128 + ((kg ^ (_r & 7)) << 4); \
  A##s##_##i0 = *reinterpret_cast<const bf16x8*>(abase + _o0); \
  A##s##_##i1 = *reinterpret_cast<const bf16x8*>(abase + (_o0 ^ 64)); }

#define WAITV(N) \
  asm volatile("s_waitcnt vmcnt(" #N ")" ::: "memory"); \
  __builtin_amdgcn_sched_barrier(0);

#define BARRIER() \
  asm volatile("s_waitcnt lgkmcnt(0)\n\ts_barrier" ::: "memory"); \
  __builtin_amdgcn_sched_barrier(0);

#define BC(x) __builtin_bit_cast(bf16x8, x)
#define MF(b_, a_, c_) __builtin_amdgcn_mfma_f32_16x16x32_bf16(BC(b_), a_, c_, 0, 0, 0)

// ---------------------------------------------------------------------------
// v10d: DIAGNOSTIC grid — 128 persistent blocks x 8 tiles (2x dispatch time
// so conv finally enters the rocprof top-5; same total work & output).
// Tile = (b, X, 4y) full z; 256 thr / 4 waves; wave M=64 (2y x 32z), N=32.
// LDS: 2 x 77-chunk buffers + 1KB dummy = 158720 B; cross-tile dbuf ledger.
// Consecutive tiles share (b,X) -> y-halo staging reads are L2-resident.
// ---------------------------------------------------------------------------
#define BUFU16 39424   // 77 * 512 u16 per buffer

#define STG(s) { \
  const int _c   = wv * 20 + (s); \
  const int _row = _c * 8 + rloc; \
  const int _rid = _row / 204; \
  const int _rem = _row - _rid * 204; \
  const int _yi  = _rem / 34; \
  const int _zid = _rem - _yi * 34; \
  const int _xin = Xs + _rid - 1; \
  const int _yin = ys0 + _yi - 1; \
  const int _zin = _zid - 1; \
  const bool _ib = (_row < 612) && ((unsigned)_xin < 32u) \
                 && ((unsigned)_yin < 32u) && ((unsigned)_zin < 32u); \
  const u16* _src = _ib \
      ? xb + ((size_t)(((bs * 32 + _xin) * 32 + _yin) * 32 + _zin) * 64 + swz * 8) \
      : zp16; \
  u16* _dst = (_c < 77) ? (bufn + _c * 512) : (xt + 78848); \
  __builtin_amdgcn_global_load_lds((const AS1 u32*)_src, (AS3 u32*)_dst, 16, 0, 0); \
  __builtin_amdgcn_sched_barrier(0); }

#define RCC4(T, YY, MT) ((((T)/9)*6 + (YY) + (((T)/3)%3))*34 + ((T)%3) + (MT)*16)

#define LOAD_A8(s, T) \
  LOADA2(s, 0, 1, RCC4(T,0,0)) \
  LOADA2(s, 2, 3, RCC4(T,0,1)) \
  LOADA2(s, 4, 5, RCC4(T,1,0)) \
  LOADA2(s, 6, 7, RCC4(T,1,1))

// acc{yy}{mt}{nt}; B: s0=nt0kb0 s1=nt0kb1 s2=nt1kb0 s3=nt1kb1; A idx=yy*4+mt*2+kb
#define MFMA16(bs, as) \
  acc000 = MF(B##bs##0, A##as##_0, acc000); acc001 = MF(B##bs##2, A##as##_0, acc001); \
  acc010 = MF(B##bs##0, A##as##_2, acc010); acc011 = MF(B##bs##2, A##as##_2, acc011); \
  acc100 = MF(B##bs##0, A##as##_4, acc100); acc101 = MF(B##bs##2, A##as##_4, acc101); \
  acc110 = MF(B##bs##0, A##as##_6, acc110); acc111 = MF(B##bs##2, A##as##_6, acc111); \
  acc000 = MF(B##bs##1, A##as##_1, acc000); acc001 = MF(B##bs##3, A##as##_1, acc001); \
  acc010 = MF(B##bs##1, A##as##_3, acc010); acc011 = MF(B##bs##3, A##as##_3, acc011); \
  acc100 = MF(B##bs##1, A##as##_5, acc100); acc101 = MF(B##bs##3, A##as##_5, acc101); \
  acc110 = MF(B##bs##1, A##as##_7, acc110); acc111 = MF(B##bs##3, A##as##_7, acc111);

__global__ __launch_bounds__(256, 1) void conv_mfma10(
    const u16* __restrict__ xb, const u16* __restrict__ zp16,
    float* __restrict__ out)
{
    extern __shared__ u16 xt[];   // 158720 B

    const int blk   = blockIdx.x;
    const int tbase = ((blk & 7) * 16 + (blk >> 3)) * 8;   // XCD-contiguous
    const int tid   = threadIdx.x;
    const int wv    = tid >> 6;
    const int lane  = tid & 63;
    const int l15   = lane & 15;
    const int kg    = lane >> 4;
    const int yh    = wv >> 1;
    const int nh    = wv & 1;
    const int rloc  = lane >> 3;
    const int swz   = (lane & 7) ^ rloc;
    const int rbase = yh * 68 + l15;

    const char* bTr = (const char*)g_kTr + nh * 4096 + lane * 16;

    u32x4 B00, B01, B02, B03, B10, B11, B12, B13,
          B20, B21, B22, B23, B30, B31, B32, B33;
    bf16x8 A0_0, A0_1, A0_2, A0_3, A0_4, A0_5, A0_6, A0_7;
    bf16x8 A1_0, A1_1, A1_2, A1_3, A1_4, A1_5, A1_6, A1_7;

    // ---- prologue: stage tile 0 into buffer 0 ----
    {
        const int ts = tbase;
        const int bs = ts >> 8, Xs = (ts >> 3) & 31, ys0 = (ts & 7) << 2;
        u16* bufn = xt;
        STG(0)  STG(1)  STG(2)  STG(3)  STG(4)
        STG(5)  STG(6)  STG(7)  STG(8)  STG(9)
        STG(10) STG(11) STG(12) STG(13) STG(14)
        STG(15) STG(16) STG(17) STG(18) STG(19)
        WAITV(0)
    }
    ISSUE_B(0, 1)
    ISSUE_B(1, 3)
    ISSUE_B(2, 4)
    BARRIER()

#pragma unroll 1
    for (int k = 0; k < 8; ++k) {
        const u16* bufk = xt + (k & 1) * BUFU16;
        u16*       bufn = xt + ((k & 1) ^ 1) * BUFU16;
        const char* abase = (const char*)bufk;

        const int tk = tbase + k;
        const int b  = tk >> 8, X = (tk >> 3) & 31, y0 = (tk & 7) << 2;
        const int ts = tbase + (k < 7 ? k + 1 : 7);        // clamp: re-stage
        const int bs = ts >> 8, Xs = (ts >> 3) & 31, ys0 = (ts & 7) << 2;

        const f32x4 z4 = {0.f, 0.f, 0.f, 0.f};
        f32x4 acc000 = z4, acc001 = z4, acc010 = z4, acc011 = z4;
        f32x4 acc100 = z4, acc101 = z4, acc110 = z4, acc111 = z4;

        LOAD_A8(0, 1)
        // taps {1,3,4,5,7,9,10,11,12,13,14,15,16,17,19,21,22,23,25}
        // ledger entry: k=0 -> 12 (3 B-sets); k>0 -> 20 (8 stores + 3 B-sets)
        STG(0)  STG(1)  ISSUE_B(3, 5)   LOAD_A8(1, 3)   WAITV(14)  MFMA16(0, 0)  // t=1
        STG(2)  STG(3)  ISSUE_B(0, 7)   LOAD_A8(0, 4)   WAITV(16)  MFMA16(1, 1)  // t=3
        STG(4)  STG(5)  ISSUE_B(1, 9)   LOAD_A8(1, 5)   WAITV(18)  MFMA16(2, 0)  // t=4
        STG(6)  STG(7)  ISSUE_B(2, 10)  LOAD_A8(0, 7)   WAITV(18)  MFMA16(3, 1)  // t=5
        STG(8)  STG(9)  ISSUE_B(3, 11)  LOAD_A8(1, 9)   WAITV(18)  MFMA16(0, 0)  // t=7
        STG(10) STG(11) ISSUE_B(0, 12)  LOAD_A8(0, 10)  WAITV(18)  MFMA16(1, 1)  // t=9
        STG(12) STG(13) ISSUE_B(1, 13)  LOAD_A8(1, 11)  WAITV(18)  MFMA16(2, 0)  // t=10
        STG(14) STG(15) ISSUE_B(2, 14)  LOAD_A8(0, 12)  WAITV(18)  MFMA16(3, 1)  // t=11
        STG(16) STG(17) ISSUE_B(3, 15)  LOAD_A8(1, 13)  WAITV(18)  MFMA16(0, 0)  // t=12
        STG(18) STG(19) ISSUE_B(0, 16)  LOAD_A8(0, 14)  WAITV(18)  MFMA16(1, 1)  // t=13
                        ISSUE_B(1, 17)  LOAD_A8(1, 15)  WAITV(16)  MFMA16(2, 0)  // t=14
                        ISSUE_B(2, 19)  LOAD_A8(0, 16)  WAITV(14)  MFMA16(3, 1)  // t=15
                        ISSUE_B(3, 21)  LOAD_A8(1, 17)  WAITV(12)  MFMA16(0, 0)  // t=16
                        ISSUE_B(0, 22)  LOAD_A8(0, 19)  WAITV(12)  MFMA16(1, 1)  // t=17
                        ISSUE_B(1, 23)  LOAD_A8(1, 21)  WAITV(12)  MFMA16(2, 0)  // t=19
                        ISSUE_B(2, 25)  LOAD_A8(0, 22)  WAITV(12)  MFMA16(3, 1)  // t=21
                                        LOAD_A8(1, 23)  WAITV(8)   MFMA16(0, 0)  // t=22
                                        LOAD_A8(0, 25)  WAITV(4)   MFMA16(1, 1)  // t=23
                                                        WAITV(0)   MFMA16(2, 0)  // t=25

        // ---- epilogue tile k: y=y0+yh*2+yy, z=mt*16+l15, ch=nh*32+nt*16+kg*4
        float* obase = out + (((size_t)(b * 32 + X) * 32 + (y0 + yh * 2)) * 32) * 64
                     + nh * 32 + kg * 4;
        *reinterpret_cast<f32x4*>(obase + l15 * 64)                    = acc000;
        *reinterpret_cast<f32x4*>(obase + l15 * 64 + 16)               = acc001;
        *reinterpret_cast<f32x4*>(obase + (16 + l15) * 64)             = acc010;
        *reinterpret_cast<f32x4*>(obase + (16 + l15) * 64 + 16)        = acc011;
        *reinterpret_cast<f32x4*>(obase + 2048 + l15 * 64)             = acc100;
        *reinterpret_cast<f32x4*>(obase + 2048 + l15 * 64 + 16)        = acc101;
        *reinterpret_cast<f32x4*>(obase + 2048 + (16 + l15) * 64)      = acc110;
        *reinterpret_cast<f32x4*>(obase + 2048 + (16 + l15) * 64 + 16) = acc111;
        __builtin_amdgcn_sched_barrier(0);

        // pre-issue next tile's first three B sets, then publish staged tile
        ISSUE_B(0, 1)
        ISSUE_B(1, 3)
        ISSUE_B(2, 4)
        BARRIER()
    }
}

// ---------------------------------------------------------------------------
// Fallback (v8, fused fp32 staging, no ws needed) — verified round 11.
// ---------------------------------------------------------------------------
#define LDSW7 24576   // u16 = 49152 B

#define RCC7(T, YY) (((T)/9)*128 + ((((T)/3)%3) + (YY))*18 + ((T)%3))

#define LOAD_A4(s, T) \
  LOADA2(s, 0, 1, RCC7(T,0)) \
  LOADA2(s, 2, 3, RCC7(T,1))

#define MFMA8(bs, as) \
  acc00 = MF(B##bs##0, A##as##_0, acc00); acc01 = MF(B##bs##2, A##as##_0, acc01); \
  acc10 = MF(B##bs##0, A##as##_2, acc10); acc11 = MF(B##bs##2, A##as##_2, acc11); \
  acc00 = MF(B##bs##1, A##as##_1, acc00); acc01 = MF(B##bs##3, A##as##_1, acc01); \
  acc10 = MF(B##bs##1, A##as##_3, acc10); acc11 = MF(B##bs##3, A##as##_3, acc11);

__global__ __launch_bounds__(256, 3) void conv_mfma8(
    const float* __restrict__ x, float* __restrict__ out)
{
    __shared__ __align__(16) u16 xt[LDSW7];

    const int bid0 = blockIdx.x;
    const int bid  = (bid0 & 7) * 256 + (bid0 >> 3);
    const int b    = bid >> 9;
    const int X    = (bid >> 4) & 31;
    const int yg   = (bid >> 1) & 7;
    const int zg   = bid & 1;
    const int y0   = yg << 2;
    const int z0   = zg << 4;
    const int tid  = threadIdx.x;
    const int wv   = tid >> 6;
    const int lane = tid & 63;
    const int l15  = lane & 15;
    const int kg   = lane >> 4;
    const int yh   = wv >> 1;
    const int nh   = wv & 1;

    const char* bTr = (const char*)g_kTr + nh * 4096 + lane * 16;

    u32x4 B00, B01, B02, B03, B10, B11, B12, B13, B20, B21, B22, B23;
    bf16x8 A0_0, A0_1, A0_2, A0_3;
    bf16x8 A1_0, A1_1, A1_2, A1_3;

    ISSUE_B(0, 1)
    ISSUE_B(1, 3)

    {
        const int rloc = lane >> 3;
        const int swz  = (lane & 7) ^ rloc;
        const int cip  = wv * 4;
        const int rip0 = cip * 8 + rloc;
#pragma unroll 1
        for (int p = 0; p < 3; ++p) {
            const int xin = X + p - 1;
#pragma unroll
            for (int j = 0; j < 4; ++j) {
                const int rip = rip0 + j * 8;
                const int yi  = rip / 18;
                const int zid = rip - yi * 18;
                const int yin = y0 + yi - 1;
                const int zin = z0 + zid - 1;
                const bool inb = (rip < 108) & ((unsigned)xin < 32u)
                               & ((unsigned)yin < 32u) & ((unsigned)zin < 32u);
                u32x4 pk = {0u, 0u, 0u, 0u};
                if (inb) {
                    const float4* s = reinterpret_cast<const float4*>(
                        x + ((size_t)(((b * 32 + xin) * 32 + yin) * 32 + zin) * 64
                             + swz * 8));
                    float4 v0 = s[0], v1 = s[1];
                    pk[0] = pack_bf(v0.x, v0.y); pk[1] = pack_bf(v0.z, v0.w);
                    pk[2] = pack_bf(v1.x, v1.y); pk[3] = pack_bf(v1.z, v1.w);
                }
                *reinterpret_cast<u32x4*>(&xt[(p * 16 + cip + j) * 512 + lane * 8]) = pk;
            }
        }
    }
    __syncthreads();

    const char* abase = reinterpret_cast<const char*>(xt);
    const int rbase = yh * 36 + l15;

    const f32x4 z4 = {0.f, 0.f, 0.f, 0.f};
    f32x4 acc00 = z4, acc01 = z4, acc10 = z4, acc11 = z4;

    LOAD_A4(0, 1)
    ISSUE_B(2, 4)   LOAD_A4(1, 3)            MFMA8(0, 0)   // t=1
    ISSUE_B(0, 5)   LOAD_A4(0, 4)            MFMA8(1, 1)   // t=3
    ISSUE_B(1, 7)   LOAD_A4(1, 5)  WAITV(8)  MFMA8(2, 0)   // t=4
    ISSUE_B(2, 9)   LOAD_A4(0, 7)  WAITV(8)  MFMA8(0, 1)   // t=5
    ISSUE_B(0, 10)  LOAD_A4(1, 9)  WAITV(8)  MFMA8(1, 0)   // t=7
    ISSUE_B(1, 11)  LOAD_A4(0, 10) WAITV(8)  MFMA8(2, 1)   // t=9
    ISSUE_B(2, 12)  LOAD_A4(1, 11) WAITV(8)  MFMA8(0, 0)   // t=10
    ISSUE_B(0, 13)  LOAD_A4(0, 12) WAITV(8)  MFMA8(1, 1)   // t=11
    ISSUE_B(1, 14)  LOAD_A4(1, 13) WAITV(8)  MFMA8(2, 0)   // t=12
    ISSUE_B(2, 15)  LOAD_A4(0, 14) WAITV(8)  MFMA8(0, 1)   // t=13
    ISSUE_B(0, 16)  LOAD_A4(1, 15) WAITV(8)  MFMA8(1, 0)   // t=14
    ISSUE_B(1, 17)  LOAD_A4(0, 16) WAITV(8)  MFMA8(2, 1)   // t=15
    ISSUE_B(2, 19)  LOAD_A4(1, 17) WAITV(8)  MFMA8(0, 0)   // t=16
    ISSUE_B(0, 21)  LOAD_A4(0, 19) WAITV(8)  MFMA8(1, 1)   // t=17
    ISSUE_B(1, 22)  LOAD_A4(1, 21) WAITV(8)  MFMA8(2, 0)   // t=19
    ISSUE_B(2, 23)  LOAD_A4(0, 22) WAITV(8)  MFMA8(0, 1)   // t=21
    ISSUE_B(0, 25)  LOAD_A4(1, 23) WAITV(8)  MFMA8(1, 0)   // t=22
                    LOAD_A4(0, 25) WAITV(4)  MFMA8(2, 1)   // t=23
                                   WAITV(0)  MFMA8(0, 0)   // t=25

    float* obase = out + ((((size_t)(b * 32 + X) * 32 + (y0 + yh * 2)) * 32) + z0) * 64
                 + nh * 32 + kg * 4;
    *reinterpret_cast<f32x4*>(obase + l15 * 64)               = acc00;
    *reinterpret_cast<f32x4*>(obase + l15 * 64 + 16)          = acc01;
    *reinterpret_cast<f32x4*>(obase + 2048 + l15 * 64)        = acc10;
    *reinterpret_cast<f32x4*>(obase + 2048 + l15 * 64 + 16)   = acc11;
}

extern "C" void kernel_launch(void* const* d_in, const int* in_sizes, int n_in,
                              void* d_out, int out_size, void* d_ws, size_t ws_size,
                              hipStream_t stream)
{
    const float* x    = (const float*)d_in[0];
    const float* Wsc0 = (const float*)d_in[1];
    const float* Wsc1 = (const float*)d_in[2];
    const float* w1   = (const float*)d_in[3];
    const float* w2   = (const float*)d_in[4];
    const float* w3   = (const float*)d_in[5];
    const float* w4   = (const float*)d_in[6];
    float* out = (float*)d_out;

    const size_t xb_bytes = (size_t)4 * 32 * 32 * 32 * 64 * 2;   // 16.8 MB
    if (ws_size >= 4096 + xb_bytes) {
        u32* zp = (u32*)d_ws;
        u16* xb = (u16*)((char*)d_ws + 4096);
        prep<<<dim3(27 + 4096), dim3(256), 0, stream>>>(Wsc0, Wsc1, w1, w2, w3, w4,
                                                        x, xb, zp);
        conv_mfma10<<<dim3(128), dim3(256), 158720, stream>>>(xb, (const u16*)zp, out);
    } else {
        prep<<<dim3(27), dim3(256), 0, stream>>>(Wsc0, Wsc1, w1, w2, w3, w4,
                                                 x, (u16*)nullptr, (u32*)nullptr);
        conv_mfma8<<<dim3(2048), dim3(256), 0, stream>>>(x, out);
    }
}

// Round 16
// 54.591 us; speedup vs baseline: 1.4412x; 1.4412x over previous
//
#include <hip/hip_runtime.h>

typedef unsigned short u16;
typedef unsigned int u32;
typedef __bf16 bf16x8 __attribute__((ext_vector_type(8)));
typedef float f32x4 __attribute__((ext_vector_type(4)));
typedef u32 u32x4 __attribute__((ext_vector_type(4)));

// kTr[((t*2+nh)*2+nt)*2+kb][lane][j] : per-lane-ordered repack -> every
// B-load is one fully-contiguous 1KB wave read (8 fully-used cachelines).
__device__ __align__(16) u16 g_kTr[27 * 8 * 512];

__device__ __forceinline__ u32 pack_bf(float a, float b) {
    u32 ua = __float_as_uint(a) + 0x8000u;   // round-half-up
    u32 ub = __float_as_uint(b) + 0x8000u;
    return __builtin_amdgcn_perm(ub, ua, 0x07060302u);
}

// ---------------------------------------------------------------------------
// build_k: kTr (+ fold self-connection into center tap). 27 blocks x 64.
// ---------------------------------------------------------------------------
__global__ __launch_bounds__(64) void build_k(
    const float* __restrict__ Wsc0, const float* __restrict__ Wsc1,
    const float* __restrict__ w1, const float* __restrict__ w2,
    const float* __restrict__ w3, const float* __restrict__ w4)
{
    const int t = blockIdx.x;
    const int c = threadIdx.x;
    const int dx = t / 9 - 1, dy = (t / 3) % 3 - 1, dz = t % 3 - 1;
    const float d = sqrtf((float)(dx * dx + dy * dy + dz * dz));
    const float step = 1.5f / 9.0f;
    float emb[8];
#pragma unroll
    for (int k = 0; k < 8; ++k) {
        float diff = (d - (float)(k + 1) * step) / step;
        float q = diff * diff;
        emb[k] = (q < 1.0f) ? 1.14136f * expf(2.0f - 2.0f / (1.0f - q)) : 0.0f;
    }
    const float dn = fmaxf(d, 1e-12f);
    const float s3 = 1.7320508075688772f;
    const float sh1[3] = { s3 * dx / dn, s3 * dy / dn, s3 * dz / dn };
    const float alpha  = 0.17677669529663687f;
    const float alpha3 = alpha * 0.57735026918962576f;

    const int base2 = ((t * 2 + (c >> 5)) * 2 + ((c >> 4) & 1)) * 2;
    const int l15c  = c & 15;
    auto put = [&](int r, float v) {
        u32 u = __float_as_uint(v);
        u += 0x7FFFu + ((u >> 16) & 1u);
        g_kTr[(base2 + (r >> 5)) * 512 + (((r >> 3) & 3) * 16 + l15c) * 8 + (r & 7)] =
            (u16)(u >> 16);
    };

    if (c < 16) {
        const int o = c;
#pragma unroll
        for (int i = 0; i < 16; ++i) {
            float W1 = 0.f, W4 = 0.f;
#pragma unroll
            for (int k = 0; k < 8; ++k) {
                W1 += emb[k] * w1[k * 256 + i * 16 + o];
                W4 += emb[k] * w4[k * 256 + i * 16 + o];
            }
            W1 *= (1.0f / 27.0f); W4 *= (1.0f / 27.0f);
            float v0 = alpha * W1;
            if (t == 13) v0 += 0.25f * Wsc0[i * 16 + o];
            put(i, v0);
            const float base = alpha3 * W4;
#pragma unroll
            for (int m = 0; m < 3; ++m) put(16 + 3 * i + m, base * sh1[m]);
        }
    } else {
        const int o = (c - 16) / 3, nc = (c - 16) % 3;
#pragma unroll
        for (int i = 0; i < 16; ++i) {
            float W2 = 0.f, W3 = 0.f;
#pragma unroll
            for (int k = 0; k < 8; ++k) {
                W2 += emb[k] * w2[k * 256 + i * 16 + o];
                W3 += emb[k] * w3[k * 256 + i * 16 + o];
            }
            W2 *= (1.0f / 27.0f); W3 *= (1.0f / 27.0f);
            put(i, alpha * W2 * sh1[nc]);
#pragma unroll
            for (int m = 0; m < 3; ++m) {
                float v = (m == nc) ? alpha * W3 : 0.0f;
                if (t == 13 && m == nc) v += 0.25f * Wsc1[i * 16 + o];
                put(16 + 3 * i + m, v);
            }
        }
    }
}

// ---------------------------------------------------------------------------
// v11: fused persistent double-buffered conv — ALL plain-C loads (compiler
// owns every waitcnt; no hand ledger, no asm loads), one sched_barrier wall
// per tap. 256 blocks x 4 tiles; tile = (b, X, 4y) full z; 4 waves;
// wave (yh,nh): M = 2y x 32z = 64, N = 32. Staging: fp32 -> pack -> ds_write
// pipelined across regions (load in region i, write in region i+2).
// ---------------------------------------------------------------------------
#define BUFU16 39424   // 77 * 512 u16 per buffer

#define WALL() __builtin_amdgcn_sched_barrier(0);

// B fragments for tap T into slot S (plain C loads from L2-resident kTr)
#define LOADB(S, T) { \
  const u32x4* _p = reinterpret_cast<const u32x4*>(bTr + (T) * 8192); \
  B##S##0 = _p[0]; B##S##1 = _p[64]; B##S##2 = _p[128]; B##S##3 = _p[192]; }

#define LOADA2(s, i0, i1, RCC) { \
  const int _r  = rbase + (RCC); \
  const int _o0 = _r * 128 + ((kg ^ (_r & 7)) << 4); \
  A##s##_##i0 = *reinterpret_cast<const bf16x8*>(abase + _o0); \
  A##s##_##i1 = *reinterpret_cast<const bf16x8*>(abase + (_o0 ^ 64)); }

#define RCC4(T, YY, MT) ((((T)/9)*6 + (YY) + (((T)/3)%3))*34 + ((T)%3) + (MT)*16)

#define LOAD_A8(s, T) \
  LOADA2(s, 0, 1, RCC4(T,0,0)) \
  LOADA2(s, 2, 3, RCC4(T,0,1)) \
  LOADA2(s, 4, 5, RCC4(T,1,0)) \
  LOADA2(s, 6, 7, RCC4(T,1,1))

// stage-load chunk (wv*20 + C) of tile (bs,Xs,ys0) into fp32 slot S
#define SLD(S, C) { \
  const int _c   = wv * 20 + (C); \
  const int _row = _c * 8 + rloc; \
  const int _rid = _row / 204; \
  const int _rem = _row - _rid * 204; \
  const int _yi  = _rem / 34; \
  const int _zid = _rem - _yi * 34; \
  const int _xin = Xs + _rid - 1; \
  const int _yin = ys0 + _yi - 1; \
  const int _zin = _zid - 1; \
  const bool _ib = (_row < 612) && ((unsigned)_xin < 32u) && \
                   ((unsigned)_yin < 32u) && ((unsigned)_zin < 32u); \
  F##S##a = (f32x4){0.f, 0.f, 0.f, 0.f}; \
  F##S##b = (f32x4){0.f, 0.f, 0.f, 0.f}; \
  if (_ib) { \
    const f32x4* _p = reinterpret_cast<const f32x4*>( \
        x + ((size_t)(((bs * 32 + _xin) * 32 + _yin) * 32 + _zin) * 64 + swz * 8)); \
    F##S##a = _p[0]; F##S##b = _p[1]; \
  } }

// pack + ds_write chunk (wv*20 + C) from slot S (chunks >= 77 don't exist)
#define SWR(S, C) { \
  const int _c = wv * 20 + (C); \
  if (_c < 77) { \
    u32x4 _pk; \
    _pk[0] = pack_bf(F##S##a[0], F##S##a[1]); \
    _pk[1] = pack_bf(F##S##a[2], F##S##a[3]); \
    _pk[2] = pack_bf(F##S##b[0], F##S##b[1]); \
    _pk[3] = pack_bf(F##S##b[2], F##S##b[3]); \
    *reinterpret_cast<u32x4*>(bufn + _c * 512 + lane * 8) = _pk; \
  } }

#define BC(x) __builtin_bit_cast(bf16x8, x)
#define MF(b_, a_, c_) __builtin_amdgcn_mfma_f32_16x16x32_bf16(BC(b_), a_, c_, 0, 0, 0)

// acc{yy}{mt}{nt}; B: s0=nt0kb0 s1=nt0kb1 s2=nt1kb0 s3=nt1kb1; A idx=yy*4+mt*2+kb
#define MFMA16(bs, as) \
  acc000 = MF(B##bs##0, A##as##_0, acc000); acc001 = MF(B##bs##2, A##as##_0, acc001); \
  acc010 = MF(B##bs##0, A##as##_2, acc010); acc011 = MF(B##bs##2, A##as##_2, acc011); \
  acc100 = MF(B##bs##0, A##as##_4, acc100); acc101 = MF(B##bs##2, A##as##_4, acc101); \
  acc110 = MF(B##bs##0, A##as##_6, acc110); acc111 = MF(B##bs##2, A##as##_6, acc111); \
  acc000 = MF(B##bs##1, A##as##_1, acc000); acc001 = MF(B##bs##3, A##as##_1, acc001); \
  acc010 = MF(B##bs##1, A##as##_3, acc010); acc011 = MF(B##bs##3, A##as##_3, acc011); \
  acc100 = MF(B##bs##1, A##as##_5, acc100); acc101 = MF(B##bs##3, A##as##_5, acc101); \
  acc110 = MF(B##bs##1, A##as##_7, acc110); acc111 = MF(B##bs##3, A##as##_7, acc111);

__global__ __launch_bounds__(256, 1) void conv_mfma11(
    const float* __restrict__ x, float* __restrict__ out)
{
    extern __shared__ u16 xt[];   // 2 * 78848 B

    const int blk   = blockIdx.x;
    const int tbase = ((blk & 7) * 32 + (blk >> 3)) * 4;   // XCD-contiguous
    const int tid   = threadIdx.x;
    const int wv    = tid >> 6;
    const int lane  = tid & 63;
    const int l15   = lane & 15;
    const int kg    = lane >> 4;
    const int yh    = wv >> 1;
    const int nh    = wv & 1;
    const int rloc  = lane >> 3;
    const int swz   = (lane & 7) ^ rloc;
    const int rbase = yh * 68 + l15;

    const char* bTr = (const char*)g_kTr + nh * 4096 + lane * 16;

    u32x4 B00, B01, B02, B03, B10, B11, B12, B13, B20, B21, B22, B23;
    bf16x8 A0_0, A0_1, A0_2, A0_3, A0_4, A0_5, A0_6, A0_7;
    bf16x8 A1_0, A1_1, A1_2, A1_3, A1_4, A1_5, A1_6, A1_7;
    f32x4 F0a, F0b, F1a, F1b, F2a, F2b, F3a, F3b;

    // ---- prologue: stage tile 0 into buffer 0 (compiler-scheduled) ----
    {
        const int ts = tbase;
        const int bs = ts >> 8, Xs = (ts >> 3) & 31, ys0 = (ts & 7) << 2;
        u16* bufn = xt;
#pragma unroll
        for (int g = 0; g < 5; ++g) {
            SLD(0, g * 4 + 0) SLD(1, g * 4 + 1) SLD(2, g * 4 + 2) SLD(3, g * 4 + 3)
            SWR(0, g * 4 + 0) SWR(1, g * 4 + 1) SWR(2, g * 4 + 2) SWR(3, g * 4 + 3)
        }
    }
    __syncthreads();

#pragma unroll 1
    for (int k = 0; k < 4; ++k) {
        const u16* bufk = xt + (k & 1) * BUFU16;
        u16*       bufn = xt + ((k & 1) ^ 1) * BUFU16;
        const char* abase = (const char*)bufk;

        const int tk = tbase + k;
        const int b  = tk >> 8, X = (tk >> 3) & 31, y0 = (tk & 7) << 2;
        const int ts = tbase + (k < 3 ? k + 1 : 3);        // clamp: re-stage
        const int bs = ts >> 8, Xs = (ts >> 3) & 31, ys0 = (ts & 7) << 2;

        const f32x4 z4 = {0.f, 0.f, 0.f, 0.f};
        f32x4 acc000 = z4, acc001 = z4, acc010 = z4, acc011 = z4;
        f32x4 acc100 = z4, acc101 = z4, acc110 = z4, acc111 = z4;

        // preamble: B(t1), B(t3), A(t1)
        LOADB(0, 1) LOADB(1, 3) LOAD_A8(0, 1)
        WALL()
        // taps {1,3,4,5,7,9,10,11,12,13,14,15,16,17,19,21,22,23,25}
        // region i: [SWR prev batch][SLD next batch][LOADB i+2][LOAD_A8 i+1][MFMA i] WALL
        SLD(0,0)  SLD(1,1)              LOADB(2, 4)  LOAD_A8(1, 3)  MFMA16(0, 0) WALL() // t=1
        SLD(2,2)  SLD(3,3)              LOADB(0, 5)  LOAD_A8(0, 4)  MFMA16(1, 1) WALL() // t=3
        SWR(0,0)  SWR(1,1)  SLD(0,4)  SLD(1,5)   LOADB(1, 7)  LOAD_A8(1, 5)  MFMA16(2, 0) WALL() // t=4
        SWR(2,2)  SWR(3,3)  SLD(2,6)  SLD(3,7)   LOADB(2, 9)  LOAD_A8(0, 7)  MFMA16(0, 1) WALL() // t=5
        SWR(0,4)  SWR(1,5)  SLD(0,8)  SLD(1,9)   LOADB(0, 10) LOAD_A8(1, 9)  MFMA16(1, 0) WALL() // t=7
        SWR(2,6)  SWR(3,7)  SLD(2,10) SLD(3,11)  LOADB(1, 11) LOAD_A8(0, 10) MFMA16(2, 1) WALL() // t=9
        SWR(0,8)  SWR(1,9)  SLD(0,12) SLD(1,13)  LOADB(2, 12) LOAD_A8(1, 11) MFMA16(0, 0) WALL() // t=10
        SWR(2,10) SWR(3,11) SLD(2,14) SLD(3,15)  LOADB(0, 13) LOAD_A8(0, 12) MFMA16(1, 1) WALL() // t=11
        SWR(0,12) SWR(1,13) SLD(0,16) SLD(1,17)  LOADB(1, 14) LOAD_A8(1, 13) MFMA16(2, 0) WALL() // t=12
        SWR(2,14) SWR(3,15) SLD(2,18) SLD(3,19)  LOADB(2, 15) LOAD_A8(0, 14) MFMA16(0, 1) WALL() // t=13
        SWR(0,16) SWR(1,17)                      LOADB(0, 16) LOAD_A8(1, 15) MFMA16(1, 0) WALL() // t=14
        SWR(2,18) SWR(3,19)                      LOADB(1, 17) LOAD_A8(0, 16) MFMA16(2, 1) WALL() // t=15
                                                 LOADB(2, 19) LOAD_A8(1, 17) MFMA16(0, 0) WALL() // t=16
                                                 LOADB(0, 21) LOAD_A8(0, 19) MFMA16(1, 1) WALL() // t=17
                                                 LOADB(1, 22) LOAD_A8(1, 21) MFMA16(2, 0) WALL() // t=19
                                                 LOADB(2, 23) LOAD_A8(0, 22) MFMA16(0, 1) WALL() // t=21
                                                 LOADB(0, 25) LOAD_A8(1, 23) MFMA16(1, 0) WALL() // t=22
                                                              LOAD_A8(0, 25) MFMA16(2, 1) WALL() // t=23
                                                                             MFMA16(0, 0) WALL() // t=25

        // ---- epilogue tile k: y=y0+yh*2+yy, z=mt*16+l15, ch=nh*32+nt*16+kg*4
        float* obase = out + (((size_t)(b * 32 + X) * 32 + (y0 + yh * 2)) * 32) * 64
                     + nh * 32 + kg * 4;
        *reinterpret_cast<f32x4*>(obase + l15 * 64)                    = acc000;
        *reinterpret_cast<f32x4*>(obase + l15 * 64 + 16)               = acc001;
        *reinterpret_cast<f32x4*>(obase + (16 + l15) * 64)             = acc010;
        *reinterpret_cast<f32x4*>(obase + (16 + l15) * 64 + 16)        = acc011;
        *reinterpret_cast<f32x4*>(obase + 2048 + l15 * 64)             = acc100;
        *reinterpret_cast<f32x4*>(obase + 2048 + l15 * 64 + 16)        = acc101;
        *reinterpret_cast<f32x4*>(obase + 2048 + (16 + l15) * 64)      = acc110;
        *reinterpret_cast<f32x4*>(obase + 2048 + (16 + l15) * 64 + 16) = acc111;

        __syncthreads();   // publish bufn, retire bufk reads (full drain ok)
    }
}

extern "C" void kernel_launch(void* const* d_in, const int* in_sizes, int n_in,
                              void* d_out, int out_size, void* d_ws, size_t ws_size,
                              hipStream_t stream)
{
    const float* x    = (const float*)d_in[0];
    const float* Wsc0 = (const float*)d_in[1];
    const float* Wsc1 = (const float*)d_in[2];
    const float* w1   = (const float*)d_in[3];
    const float* w2   = (const float*)d_in[4];
    const float* w3   = (const float*)d_in[5];
    const float* w4   = (const float*)d_in[6];
    float* out = (float*)d_out;

    build_k<<<dim3(27), dim3(64), 0, stream>>>(Wsc0, Wsc1, w1, w2, w3, w4);
    conv_mfma11<<<dim3(256), dim3(256), 2 * 78848, stream>>>(x, out);
}